// Round 1
// baseline (77.103 us; speedup 1.0000x reference)
//
#include <hip/hip_runtime.h>

#define NNODES 128
#define BATCH  32768
#define BLOCK  256
#define ROWS_PER_CHUNK 16
#define NCHUNKS (BATCH / ROWS_PER_CHUNK)   // 2048
#define GRID   512

__device__ __forceinline__ float sigmoidf_(float z) {
    return 1.0f / (1.0f + __expf(-z));
}

__device__ __forceinline__ float clipf_(float v) {
    return fminf(fmaxf(v, -100.0f), 100.0f);
}

// Per-node epilogue: given the node's 8 clipped states, its node_input,
// and per-node params, produce the 8 derivatives.
__device__ __forceinline__ void node_update(const float* xs8, float ni,
                                            const float* gi, const float* invTi,
                                            float sci, float Ri, float* f8) {
    float S0 = sigmoidf_(Ri * xs8[0]) - 0.5f;
    float S2 = sigmoidf_(Ri * xs8[2]) - 0.5f;
    float S4 = sigmoidf_(Ri * xs8[4]) - 0.5f;
    float S6 = sigmoidf_(Ri * xs8[6]) - 0.5f;
    float u1 = ni - gi[0] * S0 - gi[1] * S2 - gi[2]  * S4;
    float u3 = ni + gi[7] * S0 - gi[6] * S2 - gi[11] * S4;
    float u5 = ni + gi[4] * S0 + gi[10] * S2 - gi[3] * S4 + gi[5] * S6;
    float u7 = ni - gi[8] * S4 - gi[9] * S6;
    f8[0] = sci * xs8[1];
    f8[1] = sci * (u1 - 2.0f * xs8[1] - xs8[0] * invTi[0]) * invTi[0];
    f8[2] = sci * xs8[3];
    f8[3] = sci * (u3 - 2.0f * xs8[3] - xs8[2] * invTi[1]) * invTi[1];
    f8[4] = sci * xs8[5];
    f8[5] = sci * (u5 - 2.0f * xs8[5] - xs8[4] * invTi[2]) * invTi[2];
    f8[6] = sci * xs8[7];
    f8[7] = sci * (u7 - 2.0f * xs8[7] - xs8[6] * invTi[3]) * invTi[3];
}

__global__ __launch_bounds__(BLOCK, 2)
void cmc_kernel(const float* __restrict__ x,
                const float* __restrict__ C,
                const float* __restrict__ G,
                const float* __restrict__ T,
                const float* __restrict__ adap,
                const float* __restrict__ R,
                float* __restrict__ out)
{
    // ct: C transposed (Ct[j][i] = C[i][j], diag zeroed), XOR-swizzled so the
    // matmul's uniform-j float4 reads are contiguous 512B (conflict-free).
    __shared__ float ct[NNODES * NNODES];              // 64 KB
    __shared__ float m_lds[ROWS_PER_CHUNK][NNODES];    // 8 KB

    const int tid    = threadIdx.x;
    const int lane31 = tid & 31;
    const int lr     = tid >> 5;          // 0..7
    const int n0     = lane31 * 4;        // this thread's 4 nodes: n0..n0+3

    // ---- stage Ct once per block (transpose + zero diag + swizzle) ----
    {
        const int j4 = lane31 * 4;
        #pragma unroll
        for (int ii = 0; ii < 16; ++ii) {
            int i = lr + ii * 8;
            float4 c = *reinterpret_cast<const float4*>(C + i * NNODES + j4);
            if (i == j4 + 0) c.x = 0.0f;
            if (i == j4 + 1) c.y = 0.0f;
            if (i == j4 + 2) c.z = 0.0f;
            if (i == j4 + 3) c.w = 0.0f;
            float cv[4] = {c.x, c.y, c.z, c.w};
            #pragma unroll
            for (int k = 0; k < 4; ++k) {
                int j  = j4 + k;
                int sw = ((j >> 2) & 7) << 2;
                ct[j * NNODES + (i ^ sw)] = cv[k];
            }
        }
    }

    // ---- per-node params into registers (reused across all chunks) ----
    float g[4][12], invT[4][4], sc[4], Rr[4];
    #pragma unroll
    for (int i = 0; i < 4; ++i) {
        int n = n0 + i;
        #pragma unroll
        for (int k = 0; k < 12; ++k) g[i][k] = G[n * 12 + k];
        #pragma unroll
        for (int k = 0; k < 4; ++k) invT[i][k] = 1.0f / T[n * 4 + k];
        sc[i] = 0.1f * sigmoidf_(adap[n]);
        Rr[i] = R[n];
    }

    __syncthreads();   // ct visible to all

    for (int chunk = blockIdx.x; chunk < NCHUNKS; chunk += GRID) {
        const int r0 = chunk * ROWS_PER_CHUNK + lr;   // first row
        const int r1 = r0 + 8;                        // second row

        // ---- load + clip x for 2 rows x 4 nodes x 8 states ----
        float xv[2][32];
        {
            const float4* p0 = reinterpret_cast<const float4*>(x + (size_t)r0 * 1024 + n0 * 8);
            const float4* p1 = reinterpret_cast<const float4*>(x + (size_t)r1 * 1024 + n0 * 8);
            #pragma unroll
            for (int q = 0; q < 8; ++q) {
                float4 v = p0[q];
                xv[0][q * 4 + 0] = clipf_(v.x); xv[0][q * 4 + 1] = clipf_(v.y);
                xv[0][q * 4 + 2] = clipf_(v.z); xv[0][q * 4 + 3] = clipf_(v.w);
            }
            #pragma unroll
            for (int q = 0; q < 8; ++q) {
                float4 v = p1[q];
                xv[1][q * 4 + 0] = clipf_(v.x); xv[1][q * 4 + 1] = clipf_(v.y);
                xv[1][q * 4 + 2] = clipf_(v.z); xv[1][q * 4 + 3] = clipf_(v.w);
            }
        }

        // ---- node means -> LDS ----
        {
            float4 ma, mb;
            float* pa = &ma.x; float* pb = &mb.x;
            #pragma unroll
            for (int i = 0; i < 4; ++i) {
                float s0 = 0.0f, s1 = 0.0f;
                #pragma unroll
                for (int k = 0; k < 8; ++k) { s0 += xv[0][i * 8 + k]; s1 += xv[1][i * 8 + k]; }
                pa[i] = s0 * 0.125f; pb[i] = s1 * 0.125f;
            }
            *reinterpret_cast<float4*>(&m_lds[lr][n0])     = ma;
            *reinterpret_cast<float4*>(&m_lds[lr + 8][n0]) = mb;
        }

        __syncthreads();   // means visible

        // ---- node_input: acc[i] = sum_j m[r][j] * Ct[j][n0+i] ----
        float acc0[4] = {0, 0, 0, 0}, acc1[4] = {0, 0, 0, 0};
        #pragma unroll 8
        for (int j4 = 0; j4 < 32; ++j4) {
            float4 mA = *reinterpret_cast<const float4*>(&m_lds[lr][j4 * 4]);
            float4 mB = *reinterpret_cast<const float4*>(&m_lds[lr + 8][j4 * 4]);
            const float* pmA = &mA.x; const float* pmB = &mB.x;
            const int col = n0 ^ ((j4 & 7) << 2);
            #pragma unroll
            for (int c2 = 0; c2 < 4; ++c2) {
                int j = j4 * 4 + c2;
                float4 ct4 = *reinterpret_cast<const float4*>(&ct[j * NNODES + col]);
                float mv0 = pmA[c2], mv1 = pmB[c2];
                acc0[0] = fmaf(mv0, ct4.x, acc0[0]);
                acc0[1] = fmaf(mv0, ct4.y, acc0[1]);
                acc0[2] = fmaf(mv0, ct4.z, acc0[2]);
                acc0[3] = fmaf(mv0, ct4.w, acc0[3]);
                acc1[0] = fmaf(mv1, ct4.x, acc1[0]);
                acc1[1] = fmaf(mv1, ct4.y, acc1[1]);
                acc1[2] = fmaf(mv1, ct4.z, acc1[2]);
                acc1[3] = fmaf(mv1, ct4.w, acc1[3]);
            }
        }

        // ---- epilogue + store ----
        {
            float* o0 = out + (size_t)r0 * 1024 + n0 * 8;
            float* o1 = out + (size_t)r1 * 1024 + n0 * 8;
            #pragma unroll
            for (int i = 0; i < 4; ++i) {
                float f8[8];
                node_update(&xv[0][i * 8], acc0[i], g[i], invT[i], sc[i], Rr[i], f8);
                *reinterpret_cast<float4*>(o0 + i * 8)     = make_float4(f8[0], f8[1], f8[2], f8[3]);
                *reinterpret_cast<float4*>(o0 + i * 8 + 4) = make_float4(f8[4], f8[5], f8[6], f8[7]);
            }
            #pragma unroll
            for (int i = 0; i < 4; ++i) {
                float f8[8];
                node_update(&xv[1][i * 8], acc1[i], g[i], invT[i], sc[i], Rr[i], f8);
                *reinterpret_cast<float4*>(o1 + i * 8)     = make_float4(f8[0], f8[1], f8[2], f8[3]);
                *reinterpret_cast<float4*>(o1 + i * 8 + 4) = make_float4(f8[4], f8[5], f8[6], f8[7]);
            }
        }

        __syncthreads();   // protect m_lds before next chunk overwrites it
    }
}

extern "C" void kernel_launch(void* const* d_in, const int* in_sizes, int n_in,
                              void* d_out, int out_size, void* d_ws, size_t ws_size,
                              hipStream_t stream) {
    // setup_inputs order: t, x, node_connectivity, G, T, adaptation, R
    const float* x    = (const float*)d_in[1];
    const float* C    = (const float*)d_in[2];
    const float* G    = (const float*)d_in[3];
    const float* T    = (const float*)d_in[4];
    const float* adap = (const float*)d_in[5];
    const float* R    = (const float*)d_in[6];
    float* out        = (float*)d_out;

    hipLaunchKernelGGL(cmc_kernel, dim3(GRID), dim3(BLOCK), 0, stream,
                       x, C, G, T, adap, R, out);
}